// Round 5
// baseline (468.502 us; speedup 1.0000x reference)
//
#include <hip/hip_runtime.h>
#include <hip/hip_bf16.h>
#include <math.h>

typedef _Float16 f16x8 __attribute__((ext_vector_type(8)));
typedef _Float16 f16x4 __attribute__((ext_vector_type(4)));
typedef _Float16 f16x2 __attribute__((ext_vector_type(2)));
typedef float    f32x4 __attribute__((ext_vector_type(4)));
typedef float    f32x2 __attribute__((ext_vector_type(2)));

#define DIMD    256
#define MT      64          // rows per block
#define BT      256         // 4 waves; each wave owns 16 rows x 256 cols
#define KSTEPS  26
#define EXP_C   7.2134752044448170f   // log2(e)/TEMP, TEMP=0.2
#define LOG2E   1.4426950408889634f   // le5 = (mask-M)*log2e = log2(E)/5
#define INV_1MP 1.1111111111111112f   // 1/(1-P), P=0.1

// ---- packed-f32 VALU helpers (VOP3P, 2x f32 per instruction) -------------
static __device__ __forceinline__ f32x2 pk_fma(f32x2 a, f32x2 b, f32x2 c) {
    f32x2 d;
    asm("v_pk_fma_f32 %0, %1, %2, %3" : "=v"(d) : "v"(a), "v"(b), "v"(c));
    return d;
}
static __device__ __forceinline__ f32x2 pk_mul(f32x2 a, f32x2 b) {
    f32x2 d;
    asm("v_pk_mul_f32 %0, %1, %2" : "=v"(d) : "v"(a), "v"(b));
    return d;
}
static __device__ __forceinline__ f32x2 pk_add(f32x2 a, f32x2 b) {
    f32x2 d;
    asm("v_pk_add_f32 %0, %1, %2" : "=v"(d) : "v"(a), "v"(b));
    return d;
}

// ---- DPP row_ror cross-lane (16-lane groups, no DS ops) ------------------
template<int CTRL>
static __device__ __forceinline__ float dpp_ror(float s) {
    return __builtin_bit_cast(float, __builtin_amdgcn_update_dpp(
        0, __builtin_bit_cast(int, s), CTRL, 0xf, 0xf, false));
}
static __device__ __forceinline__ float row16_sum(float s) {
    s += dpp_ror<0x128>(s);   // ror:8
    s += dpp_ror<0x124>(s);   // ror:4
    s += dpp_ror<0x122>(s);   // ror:2
    s += dpp_ror<0x121>(s);   // ror:1
    return s;
}
static __device__ __forceinline__ float row16_max(float m) {
    m = fmaxf(m, dpp_ror<0x128>(m));
    m = fmaxf(m, dpp_ror<0x124>(m));
    m = fmaxf(m, dpp_ror<0x122>(m));
    m = fmaxf(m, dpp_ror<0x121>(m));
    return m;
}

// ---- pre-kernel: W[c][k] fp32 -> frag-major fp16 hi/lo --------------------
// Tile (kt,ct): 64 lanes x 8 fp16. Lane l: col=ct*16+(l&15), k=kt*32+(l>>4)*8..+7
__global__ __launch_bounds__(256)
void w_conv_kernel(const float* __restrict__ W, f16x8* __restrict__ ws) {
    int gid  = blockIdx.x * 256 + threadIdx.x;   // 0..8191
    int tile = gid >> 6;                         // kt*16+ct
    int lane = gid & 63;
    int kt = tile >> 4, ct = tile & 15;
    int col = ct * 16 + (lane & 15);
    int k0  = kt * 32 + (lane >> 4) * 8;
    const float* wr = W + col * 256 + k0;
    float4 f01 = *(const float4*)wr;
    float4 f23 = *(const float4*)(wr + 4);
    float wv[8] = {f01.x, f01.y, f01.z, f01.w, f23.x, f23.y, f23.z, f23.w};
    f16x8 hi, lo;
    #pragma unroll
    for (int j = 0; j < 8; ++j) {
        _Float16 h = (_Float16)wv[j];
        hi[j] = h;
        lo[j] = (_Float16)(wv[j] - (float)h);
    }
    ws[tile * 64 + lane]        = hi;
    ws[8192 + tile * 64 + lane] = lo;
}

// ---- main fused kernel ----------------------------------------------------
// LDS: A fp16 [64 rows][256 cols], 32 KB, byte-XOR swizzle:
//   byte = row*512 + ((col*2) ^ ((row&7)<<4))
__global__ __launch_bounds__(BT, 4)
void sad_mfma_kernel(const float* __restrict__ feat,
                     const float* __restrict__ bias,
                     const f16x8* __restrict__ ws,
                     float* __restrict__ out,
                     int N)
{
    __shared__ __align__(16) unsigned char smem[MT * 512];  // 32 KB

    const int tid  = threadIdx.x;
    const int lane = tid & 63;
    const int wv   = tid >> 6;           // wave 0..3, owns rows wv*16..+15
    const long long n0 = (long long)blockIdx.x * MT;

    // ---- stage 64 feature rows -> fp16 LDS (swizzled) ----
    const float4* fvec = (const float4*)feat;
    #pragma unroll
    for (int i = 0; i < 16; ++i) {
        int flat4 = i * BT + tid;            // float4 index over [64 rows][64 f4]
        int row = flat4 >> 6;
        int c4  = flat4 & 63;
        long long grow = n0 + row;
        if (grow >= N) grow = N - 1;
        float4 f = fvec[grow * 64 + c4];
        f16x4 h4;
        h4[0] = (_Float16)f.x; h4[1] = (_Float16)f.y;
        h4[2] = (_Float16)f.z; h4[3] = (_Float16)f.w;
        int off = row * 512 + ((c4 * 8) ^ ((row & 7) << 4));
        *(f16x4*)(smem + off) = h4;
    }
    __syncthreads();

    // ---- GEMM: acc[ct][p] -> col = ct*16+(lane&15), row = wv*16+(lane>>4)*4+p
    f32x4 acc[16];
    #pragma unroll
    for (int ct = 0; ct < 16; ++ct) {
        float b = bias[ct * 16 + (lane & 15)];
        acc[ct] = f32x4{b, b, b, b};
    }

    const int arow  = wv * 16 + (lane & 15);
    const int swzA  = (arow & 7) << 4;
    const int abase = arow * 512;
    const int kgrp  = (lane >> 4) * 16;

    #pragma unroll
    for (int kt = 0; kt < 8; ++kt) {
        int kbyte = kt * 64 + kgrp;
        f16x8 a8 = *(const f16x8*)(smem + abase + (kbyte ^ swzA));
        #pragma unroll
        for (int ct = 0; ct < 16; ++ct) {
            f16x8 bh = ws[(kt * 16 + ct) * 64 + lane];
            f16x8 bl = ws[8192 + (kt * 16 + ct) * 64 + lane];
            acc[ct] = __builtin_amdgcn_mfma_f32_16x16x32_f16(a8, bh, acc[ct], 0, 0, 0);
            acc[ct] = __builtin_amdgcn_mfma_f32_16x16x32_f16(a8, bl, acc[ct], 0, 0, 0);
        }
    }

    // ---- row max per plane: 16 cts in-thread + DPP 16-lane reduce ----
    float M[4];
    #pragma unroll
    for (int p = 0; p < 4; ++p) {
        float m = acc[0][p];
        #pragma unroll
        for (int ct = 1; ct < 16; ++ct) m = fmaxf(m, acc[ct][p]);
        M[p] = row16_max(m);
    }

    const f32x2 one2 = f32x2{1.0f, 1.0f};

    // ---- two plane-pairs: init -> 26 peel iters -> epilogue, small live set
    #pragma unroll
    for (int pp = 0; pp < 2; ++pp) {
        const int p0 = 2 * pp, p1 = p0 + 1;

        // q = E = exp2((mask-M)*C); le5 = (mask-M)*log2e (fp16) for z-recovery
        f32x2 qa[8], qb[8];
        f16x2 lea[8], leb[8];
        #pragma unroll
        for (int cc = 0; cc < 8; ++cc) {
            float d0 = acc[2 * cc][p0]     - M[p0];
            float d1 = acc[2 * cc + 1][p0] - M[p0];
            float e0 = acc[2 * cc][p1]     - M[p1];
            float e1 = acc[2 * cc + 1][p1] - M[p1];
            qa[cc] = f32x2{__builtin_amdgcn_exp2f(d0 * EXP_C),
                           __builtin_amdgcn_exp2f(d1 * EXP_C)};
            qb[cc] = f32x2{__builtin_amdgcn_exp2f(e0 * EXP_C),
                           __builtin_amdgcn_exp2f(e1 * EXP_C)};
            lea[cc] = f16x2{(_Float16)(d0 * LOG2E), (_Float16)(d1 * LOG2E)};
            leb[cc] = f16x2{(_Float16)(e0 * LOG2E), (_Float16)(e1 * LOG2E)};
        }

        // 26 peeling steps on q = E*z^5:  S=sum(q); r=1-q/S; q *= r^5
        #pragma unroll 1
        for (int it = 0; it < KSTEPS; ++it) {
            f32x2 sa2 = pk_add(pk_add(pk_add(qa[0], qa[1]), pk_add(qa[2], qa[3])),
                               pk_add(pk_add(qa[4], qa[5]), pk_add(qa[6], qa[7])));
            f32x2 sb2 = pk_add(pk_add(pk_add(qb[0], qb[1]), pk_add(qb[2], qb[3])),
                               pk_add(pk_add(qb[4], qb[5]), pk_add(qb[6], qb[7])));
            float sa = row16_sum(sa2.x + sa2.y);
            float sb = row16_sum(sb2.x + sb2.y);
            sa = fmaxf(sa, 1e-30f);
            sb = fmaxf(sb, 1e-30f);
            float ra = __builtin_amdgcn_rcpf(sa);
            float rb = __builtin_amdgcn_rcpf(sb);
            f32x2 nra = f32x2{-ra, -ra};
            f32x2 nrb = f32x2{-rb, -rb};
            #pragma unroll
            for (int cc = 0; cc < 8; ++cc) {
                f32x2 r  = pk_fma(qa[cc], nra, one2);   // 1 - q/S
                f32x2 s  = pk_fma(qb[cc], nrb, one2);
                f32x2 r2 = pk_mul(r, r);
                f32x2 s2 = pk_mul(s, s);
                f32x2 r4 = pk_mul(r2, r2);
                f32x2 s4 = pk_mul(s2, s2);
                f32x2 r5 = pk_mul(r4, r);
                f32x2 s5 = pk_mul(s4, s);
                qa[cc] = pk_mul(qa[cc], r5);
                qb[cc] = pk_mul(qb[cc], s5);
            }
        }

        // epilogue for both planes: z = exp2(0.2*log2(q) - le5); out = f*z/0.9
        #pragma unroll
        for (int half = 0; half < 2; ++half) {
            int p = half ? p1 : p0;
            const f32x2* q  = half ? qb  : qa;
            const f16x2* le = half ? leb : lea;
            int row = wv * 16 + (lane >> 4) * 4 + p;
            long long grow = n0 + row;
            if (grow < N) {
                int swz = (row & 7) << 4;
                float* orow = out + grow * 256;
                #pragma unroll
                for (int cc = 0; cc < 8; ++cc) {
                    #pragma unroll
                    for (int h = 0; h < 2; ++h) {
                        int col = (2 * cc + h) * 16 + (lane & 15);
                        float qv  = fmaxf(h ? q[cc].y : q[cc].x, 0.0f);
                        float le5 = (float)le[cc][h];
                        float zz  = __builtin_amdgcn_exp2f(
                            fmaf(__builtin_amdgcn_logf(qv), 0.2f, -le5));
                        int off = row * 512 + ((col * 2) ^ swz);
                        float fval = (float)(*(const _Float16*)(smem + off));
                        orow[col] = fval * (zz * INV_1MP);
                    }
                }
            }
        }
    }
}

extern "C" void kernel_launch(void* const* d_in, const int* in_sizes, int n_in,
                              void* d_out, int out_size, void* d_ws, size_t ws_size,
                              hipStream_t stream) {
    const float* feat = (const float*)d_in[0];
    const float* W    = (const float*)d_in[1];
    const float* bias = (const float*)d_in[2];
    float* out = (float*)d_out;
    int N = in_sizes[0] / DIMD;

    // 1) W -> frag-major fp16 hi/lo in workspace (256 KB)
    w_conv_kernel<<<32, 256, 0, stream>>>(W, (f16x8*)d_ws);

    // 2) fused mask-GEMM + per-pair 26-step peeling (q-form) + output
    int grid = (int)((N + MT - 1) / MT);
    sad_mfma_kernel<<<grid, BT, 0, stream>>>(feat, bias, (const f16x8*)d_ws, out, N);
}

// Round 6
// 356.071 us; speedup vs baseline: 1.3158x; 1.3158x over previous
//
#include <hip/hip_runtime.h>
#include <hip/hip_bf16.h>
#include <math.h>

typedef _Float16 f16x8 __attribute__((ext_vector_type(8)));
typedef _Float16 f16x4 __attribute__((ext_vector_type(4)));
typedef float    f32x4 __attribute__((ext_vector_type(4)));
typedef float    f32x2 __attribute__((ext_vector_type(2)));

#define DIMD    256
#define MT      64          // rows per block
#define BT      256         // 4 waves; each wave owns 16 rows x 256 cols
#define KSTEPS  26
#define EXP_C   7.2134752044448170f   // log2(e)/TEMP, TEMP=0.2
#define INV_1MP 1.1111111111111112f   // 1/(1-P), P=0.1

// ---- packed-f32 VALU helpers (VOP3P, 2x f32 per instruction) -------------
static __device__ __forceinline__ f32x2 pk_fma(f32x2 a, f32x2 b, f32x2 c) {
    f32x2 d;
    asm("v_pk_fma_f32 %0, %1, %2, %3" : "=v"(d) : "v"(a), "v"(b), "v"(c));
    return d;
}
static __device__ __forceinline__ f32x2 pk_mul(f32x2 a, f32x2 b) {
    f32x2 d;
    asm("v_pk_mul_f32 %0, %1, %2" : "=v"(d) : "v"(a), "v"(b));
    return d;
}
static __device__ __forceinline__ f32x2 pk_add(f32x2 a, f32x2 b) {
    f32x2 d;
    asm("v_pk_add_f32 %0, %1, %2" : "=v"(d) : "v"(a), "v"(b));
    return d;
}

// ---- DPP row_ror cross-lane (16-lane groups, no DS ops) ------------------
template<int CTRL>
static __device__ __forceinline__ float dpp_ror(float s) {
    return __builtin_bit_cast(float, __builtin_amdgcn_update_dpp(
        0, __builtin_bit_cast(int, s), CTRL, 0xf, 0xf, false));
}
static __device__ __forceinline__ float row16_sum(float s) {
    s += dpp_ror<0x128>(s);   // ror:8
    s += dpp_ror<0x124>(s);   // ror:4
    s += dpp_ror<0x122>(s);   // ror:2
    s += dpp_ror<0x121>(s);   // ror:1
    return s;
}
static __device__ __forceinline__ float row16_max(float m) {
    m = fmaxf(m, dpp_ror<0x128>(m));
    m = fmaxf(m, dpp_ror<0x124>(m));
    m = fmaxf(m, dpp_ror<0x122>(m));
    m = fmaxf(m, dpp_ror<0x121>(m));
    return m;
}

// ---- pre-kernel: W[c][k] fp32 -> frag-major fp16 (single plane) ----------
// Tile (kt,ct): 64 lanes x 8 fp16. Lane l: col=ct*16+(l&15), k=kt*32+(l>>4)*8..+7
// ws: [128 tiles][64 lanes] = 128 KB
__global__ __launch_bounds__(256)
void w_conv_kernel(const float* __restrict__ W, f16x8* __restrict__ ws) {
    int gid  = blockIdx.x * 256 + threadIdx.x;   // 0..8191
    int tile = gid >> 6;                         // kt*16+ct
    int lane = gid & 63;
    int kt = tile >> 4, ct = tile & 15;
    int col = ct * 16 + (lane & 15);
    int k0  = kt * 32 + (lane >> 4) * 8;
    const float* wr = W + col * 256 + k0;
    float4 f01 = *(const float4*)wr;
    float4 f23 = *(const float4*)(wr + 4);
    float wv[8] = {f01.x, f01.y, f01.z, f01.w, f23.x, f23.y, f23.z, f23.w};
    f16x8 hi;
    #pragma unroll
    for (int j = 0; j < 8; ++j) hi[j] = (_Float16)wv[j];
    ws[tile * 64 + lane] = hi;
}

// ---- main fused kernel ----------------------------------------------------
// LDS: A fp16 [64 rows][256 cols], 32 KB, byte-XOR swizzle:
//   byte = row*512 + ((col*2) ^ ((row&7)<<4))
__global__ __launch_bounds__(BT, 4)
void sad_mfma_kernel(const float* __restrict__ feat,
                     const float* __restrict__ bias,
                     const f16x8* __restrict__ ws,
                     float* __restrict__ out,
                     int N)
{
    __shared__ __align__(16) unsigned char smem[MT * 512];  // 32 KB

    const int tid  = threadIdx.x;
    const int lane = tid & 63;
    const int wv   = tid >> 6;           // wave 0..3, owns rows wv*16..+15
    const long long n0 = (long long)blockIdx.x * MT;

    // ---- stage 64 feature rows -> fp16 LDS (swizzled) ----
    const float4* fvec = (const float4*)feat;
    #pragma unroll
    for (int i = 0; i < 16; ++i) {
        int flat4 = i * BT + tid;            // float4 index over [64 rows][64 f4]
        int row = flat4 >> 6;
        int c4  = flat4 & 63;
        long long grow = n0 + row;
        if (grow >= N) grow = N - 1;
        float4 f = fvec[grow * 64 + c4];
        f16x4 h4;
        h4[0] = (_Float16)f.x; h4[1] = (_Float16)f.y;
        h4[2] = (_Float16)f.z; h4[3] = (_Float16)f.w;
        int off = row * 512 + ((c4 * 8) ^ ((row & 7) << 4));
        *(f16x4*)(smem + off) = h4;
    }
    __syncthreads();

    // ---- GEMM: acc[ct][p] -> col = ct*16+(lane&15), row = wv*16+(lane>>4)*4+p
    f32x4 acc[16];
    #pragma unroll
    for (int ct = 0; ct < 16; ++ct) {
        float b = bias[ct * 16 + (lane & 15)];
        acc[ct] = f32x4{b, b, b, b};
    }

    const int arow  = wv * 16 + (lane & 15);
    const int swzA  = (arow & 7) << 4;
    const int abase = arow * 512;
    const int kgrp  = (lane >> 4) * 16;

    #pragma unroll
    for (int kt = 0; kt < 8; ++kt) {
        int kbyte = kt * 64 + kgrp;
        f16x8 a8 = *(const f16x8*)(smem + abase + (kbyte ^ swzA));
        #pragma unroll
        for (int ct = 0; ct < 16; ++ct) {
            f16x8 bh = ws[(kt * 16 + ct) * 64 + lane];
            acc[ct] = __builtin_amdgcn_mfma_f32_16x16x32_f16(a8, bh, acc[ct], 0, 0, 0);
        }
    }

    // ---- row max per plane: 16 cts in-thread + DPP 16-lane reduce ----
    float M[4];
    #pragma unroll
    for (int p = 0; p < 4; ++p) {
        float m = acc[0][p];
        #pragma unroll
        for (int ct = 1; ct < 16; ++ct) m = fmaxf(m, acc[ct][p]);
        M[p] = row16_max(m);
    }

    const f32x2 one2 = f32x2{1.0f, 1.0f};

    // ---- two plane-pairs: init -> 26 peel iters -> epilogue ----
    // State per pair: E (softmax numerator base) + z (remaining weight), f32.
    #pragma unroll
    for (int pp = 0; pp < 2; ++pp) {
        const int p0 = 2 * pp, p1 = p0 + 1;

        f32x2 Ea[8], Eb[8], za[8], zb[8];
        #pragma unroll
        for (int cc = 0; cc < 8; ++cc) {
            float d0 = acc[2 * cc][p0]     - M[p0];
            float d1 = acc[2 * cc + 1][p0] - M[p0];
            float e0 = acc[2 * cc][p1]     - M[p1];
            float e1 = acc[2 * cc + 1][p1] - M[p1];
            Ea[cc] = f32x2{__builtin_amdgcn_exp2f(d0 * EXP_C),
                           __builtin_amdgcn_exp2f(d1 * EXP_C)};
            Eb[cc] = f32x2{__builtin_amdgcn_exp2f(e0 * EXP_C),
                           __builtin_amdgcn_exp2f(e1 * EXP_C)};
            za[cc] = f32x2{1.0f, 1.0f};
            zb[cc] = f32x2{1.0f, 1.0f};
        }

        // 26 peeling steps: t=E*z^5; S=sum(t); z -= (t/S)*z
        #pragma unroll 1
        for (int it = 0; it < KSTEPS; ++it) {
            f32x2 ta[8], tb[8];
            #pragma unroll
            for (int cc = 0; cc < 8; ++cc) {
                f32x2 a2 = pk_mul(za[cc], za[cc]);
                f32x2 b2 = pk_mul(zb[cc], zb[cc]);
                f32x2 a4 = pk_mul(a2, a2);
                f32x2 b4 = pk_mul(b2, b2);
                f32x2 a5 = pk_mul(a4, za[cc]);
                f32x2 b5 = pk_mul(b4, zb[cc]);
                ta[cc] = pk_mul(Ea[cc], a5);
                tb[cc] = pk_mul(Eb[cc], b5);
            }
            f32x2 sa2 = pk_add(pk_add(pk_add(ta[0], ta[1]), pk_add(ta[2], ta[3])),
                               pk_add(pk_add(ta[4], ta[5]), pk_add(ta[6], ta[7])));
            f32x2 sb2 = pk_add(pk_add(pk_add(tb[0], tb[1]), pk_add(tb[2], tb[3])),
                               pk_add(pk_add(tb[4], tb[5]), pk_add(tb[6], tb[7])));
            float sa = row16_sum(sa2.x + sa2.y);
            float sb = row16_sum(sb2.x + sb2.y);
            sa = fmaxf(sa, 1e-30f);
            sb = fmaxf(sb, 1e-30f);
            float ra = __builtin_amdgcn_rcpf(sa);
            float rb = __builtin_amdgcn_rcpf(sb);
            f32x2 nra = f32x2{-ra, -ra};
            f32x2 nrb = f32x2{-rb, -rb};
            #pragma unroll
            for (int cc = 0; cc < 8; ++cc) {
                f32x2 ua = pk_mul(ta[cc], za[cc]);      // t*z
                f32x2 ub = pk_mul(tb[cc], zb[cc]);
                za[cc] = pk_fma(ua, nra, za[cc]);       // z -= t*z/S
                zb[cc] = pk_fma(ub, nrb, zb[cc]);
            }
        }

        // epilogue: out = f * z / (1-P)  (z exact in f32, no recovery math)
        #pragma unroll
        for (int half = 0; half < 2; ++half) {
            int p = half ? p1 : p0;
            const f32x2* z = half ? zb : za;
            int row = wv * 16 + (lane >> 4) * 4 + p;
            long long grow = n0 + row;
            if (grow < N) {
                int swz = (row & 7) << 4;
                float* orow = out + grow * 256;
                #pragma unroll
                for (int cc = 0; cc < 8; ++cc) {
                    #pragma unroll
                    for (int h = 0; h < 2; ++h) {
                        int col = (2 * cc + h) * 16 + (lane & 15);
                        float zz = h ? z[cc].y : z[cc].x;
                        int off = row * 512 + ((col * 2) ^ swz);
                        float fval = (float)(*(const _Float16*)(smem + off));
                        orow[col] = fval * (zz * INV_1MP);
                    }
                }
            }
        }
    }
}

extern "C" void kernel_launch(void* const* d_in, const int* in_sizes, int n_in,
                              void* d_out, int out_size, void* d_ws, size_t ws_size,
                              hipStream_t stream) {
    const float* feat = (const float*)d_in[0];
    const float* W    = (const float*)d_in[1];
    const float* bias = (const float*)d_in[2];
    float* out = (float*)d_out;
    int N = in_sizes[0] / DIMD;

    // 1) W -> frag-major fp16 in workspace (128 KB)
    w_conv_kernel<<<32, 256, 0, stream>>>(W, (f16x8*)d_ws);

    // 2) fused mask-GEMM (single fp16 pass) + peeling (E,z-form) + output
    int grid = (int)((N + MT - 1) / MT);
    sad_mfma_kernel<<<grid, BT, 0, stream>>>(feat, bias, (const f16x8*)d_ws, out, N);
}

// Round 7
// 343.510 us; speedup vs baseline: 1.3639x; 1.0366x over previous
//
#include <hip/hip_runtime.h>
#include <hip/hip_bf16.h>
#include <math.h>

typedef _Float16 f16x8 __attribute__((ext_vector_type(8)));
typedef _Float16 f16x4 __attribute__((ext_vector_type(4)));
typedef float    f32x4 __attribute__((ext_vector_type(4)));
typedef float    f32x2 __attribute__((ext_vector_type(2)));

#define DIMD    256
#define MT      64          // rows per block
#define BT      256         // 4 waves; each wave owns 16 rows x 256 cols
#define KSTEPS  26
#define EXP_C   7.2134752044448170f   // log2(e)/TEMP, TEMP=0.2
#define INV_1MP 1.1111111111111112f   // 1/(1-P), P=0.1

// ---- packed-f32 VALU helpers (VOP3P, 2x f32 per instruction) -------------
static __device__ __forceinline__ f32x2 pk_fma(f32x2 a, f32x2 b, f32x2 c) {
    f32x2 d;
    asm("v_pk_fma_f32 %0, %1, %2, %3" : "=v"(d) : "v"(a), "v"(b), "v"(c));
    return d;
}
static __device__ __forceinline__ f32x2 pk_mul(f32x2 a, f32x2 b) {
    f32x2 d;
    asm("v_pk_mul_f32 %0, %1, %2" : "=v"(d) : "v"(a), "v"(b));
    return d;
}
static __device__ __forceinline__ f32x2 pk_add(f32x2 a, f32x2 b) {
    f32x2 d;
    asm("v_pk_add_f32 %0, %1, %2" : "=v"(d) : "v"(a), "v"(b));
    return d;
}

// ---- DPP row_ror cross-lane (16-lane groups, no DS ops) ------------------
template<int CTRL>
static __device__ __forceinline__ float dpp_ror(float s) {
    return __builtin_bit_cast(float, __builtin_amdgcn_update_dpp(
        0, __builtin_bit_cast(int, s), CTRL, 0xf, 0xf, false));
}
static __device__ __forceinline__ float row16_sum(float s) {
    s += dpp_ror<0x128>(s);   // ror:8
    s += dpp_ror<0x124>(s);   // ror:4
    s += dpp_ror<0x122>(s);   // ror:2
    s += dpp_ror<0x121>(s);   // ror:1
    return s;
}
static __device__ __forceinline__ float row16_max(float m) {
    m = fmaxf(m, dpp_ror<0x128>(m));
    m = fmaxf(m, dpp_ror<0x124>(m));
    m = fmaxf(m, dpp_ror<0x122>(m));
    m = fmaxf(m, dpp_ror<0x121>(m));
    return m;
}

// ---- pre-kernel: W[c][k] fp32 -> frag-major fp16 (single plane) ----------
// Tile (kt,ct): 64 lanes x 8 fp16. Lane l: col=ct*16+(l&15), k=kt*32+(l>>4)*8..+7
// ws: [128 tiles][64 lanes] = 128 KB
__global__ __launch_bounds__(256)
void w_conv_kernel(const float* __restrict__ W, f16x8* __restrict__ ws) {
    int gid  = blockIdx.x * 256 + threadIdx.x;   // 0..8191
    int tile = gid >> 6;                         // kt*16+ct
    int lane = gid & 63;
    int kt = tile >> 4, ct = tile & 15;
    int col = ct * 16 + (lane & 15);
    int k0  = kt * 32 + (lane >> 4) * 8;
    const float* wr = W + col * 256 + k0;
    float4 f01 = *(const float4*)wr;
    float4 f23 = *(const float4*)(wr + 4);
    float wv[8] = {f01.x, f01.y, f01.z, f01.w, f23.x, f23.y, f23.z, f23.w};
    f16x8 hi;
    #pragma unroll
    for (int j = 0; j < 8; ++j) hi[j] = (_Float16)wv[j];
    ws[tile * 64 + lane] = hi;
}

// ---- main fused kernel ----------------------------------------------------
// LDS: A fp16 [64 rows][256 cols], 32 KB, byte-XOR swizzle:
//   byte = row*512 + ((col*2) ^ ((row&7)<<4))
__global__ __launch_bounds__(BT, 4)
void sad_mfma_kernel(const float* __restrict__ feat,
                     const float* __restrict__ bias,
                     const f16x8* __restrict__ ws,
                     float* __restrict__ out,
                     int N)
{
    __shared__ __align__(16) unsigned char smem[MT * 512];  // 32 KB

    const int tid  = threadIdx.x;
    const int lane = tid & 63;
    const int wv   = tid >> 6;           // wave 0..3, owns rows wv*16..+15
    const long long n0 = (long long)blockIdx.x * MT;

    // ---- stage 64 feature rows -> fp16 LDS (swizzled) ----
    const float4* fvec = (const float4*)feat;
    #pragma unroll
    for (int i = 0; i < 16; ++i) {
        int flat4 = i * BT + tid;            // float4 index over [64 rows][64 f4]
        int row = flat4 >> 6;
        int c4  = flat4 & 63;
        long long grow = n0 + row;
        if (grow >= N) grow = N - 1;
        float4 f = fvec[grow * 64 + c4];
        f16x4 h4;
        h4[0] = (_Float16)f.x; h4[1] = (_Float16)f.y;
        h4[2] = (_Float16)f.z; h4[3] = (_Float16)f.w;
        int off = row * 512 + ((c4 * 8) ^ ((row & 7) << 4));
        *(f16x4*)(smem + off) = h4;
    }
    __syncthreads();

    // ---- GEMM: acc[ct][p] -> col = ct*16+(lane&15), row = wv*16+(lane>>4)*4+p
    f32x4 acc[16];
    #pragma unroll
    for (int ct = 0; ct < 16; ++ct) {
        float b = bias[ct * 16 + (lane & 15)];
        acc[ct] = f32x4{b, b, b, b};
    }

    const int arow  = wv * 16 + (lane & 15);
    const int swzA  = (arow & 7) << 4;
    const int abase = arow * 512;
    const int kgrp  = (lane >> 4) * 16;

    #pragma unroll
    for (int kt = 0; kt < 8; ++kt) {
        int kbyte = kt * 64 + kgrp;
        f16x8 a8 = *(const f16x8*)(smem + abase + (kbyte ^ swzA));
        #pragma unroll
        for (int ct = 0; ct < 16; ++ct) {
            f16x8 bh = ws[(kt * 16 + ct) * 64 + lane];
            acc[ct] = __builtin_amdgcn_mfma_f32_16x16x32_f16(a8, bh, acc[ct], 0, 0, 0);
        }
    }

    // ---- row max per plane: 16 cts in-thread + DPP 16-lane reduce ----
    float M[4];
    #pragma unroll
    for (int p = 0; p < 4; ++p) {
        float m = acc[0][p];
        #pragma unroll
        for (int ct = 1; ct < 16; ++ct) m = fmaxf(m, acc[ct][p]);
        M[p] = row16_max(m);
    }

    const f32x2 one2 = f32x2{1.0f, 1.0f};

    // ---- one plane at a time: init -> 26 peel iters -> epilogue ----
    // Live set per plane loop: E[8] + z[8] + t[8] temps + misc < 64 VGPRs,
    // so nothing round-trips through AGPRs inside the hot loop.
    #pragma unroll 1
    for (int p = 0; p < 4; ++p) {
        f32x2 E[8], z[8];
        #pragma unroll
        for (int cc = 0; cc < 8; ++cc) {
            float d0 = acc[2 * cc][p]     - M[p];
            float d1 = acc[2 * cc + 1][p] - M[p];
            E[cc] = f32x2{__builtin_amdgcn_exp2f(d0 * EXP_C),
                          __builtin_amdgcn_exp2f(d1 * EXP_C)};
            z[cc] = f32x2{1.0f, 1.0f};
        }

        // 26 peeling steps: t=E*z^5; S=sum(t); z -= (t/S)*z
        #pragma unroll 1
        for (int it = 0; it < KSTEPS; ++it) {
            f32x2 t[8];
            #pragma unroll
            for (int cc = 0; cc < 8; ++cc) {
                f32x2 z2 = pk_mul(z[cc], z[cc]);
                f32x2 z4 = pk_mul(z2, z2);
                f32x2 z5 = pk_mul(z4, z[cc]);
                t[cc] = pk_mul(E[cc], z5);
            }
            f32x2 s2 = pk_add(pk_add(pk_add(t[0], t[1]), pk_add(t[2], t[3])),
                              pk_add(pk_add(t[4], t[5]), pk_add(t[6], t[7])));
            float s = row16_sum(s2.x + s2.y);
            s = fmaxf(s, 1e-30f);
            float rinv = __builtin_amdgcn_rcpf(s);
            f32x2 nr = f32x2{-rinv, -rinv};
            #pragma unroll
            for (int cc = 0; cc < 8; ++cc) {
                f32x2 u = pk_mul(t[cc], z[cc]);     // t*z
                z[cc] = pk_fma(u, nr, z[cc]);       // z -= t*z/S
            }
        }

        // epilogue: out = f * z / (1-P)
        int row = wv * 16 + (lane >> 4) * 4 + p;
        long long grow = n0 + row;
        if (grow < N) {
            int swz = (row & 7) << 4;
            float* orow = out + grow * 256;
            #pragma unroll
            for (int cc = 0; cc < 8; ++cc) {
                #pragma unroll
                for (int h = 0; h < 2; ++h) {
                    int col = (2 * cc + h) * 16 + (lane & 15);
                    float zz = h ? z[cc].y : z[cc].x;
                    int off = row * 512 + ((col * 2) ^ swz);
                    float fval = (float)(*(const _Float16*)(smem + off));
                    orow[col] = fval * (zz * INV_1MP);
                }
            }
        }
    }
}

extern "C" void kernel_launch(void* const* d_in, const int* in_sizes, int n_in,
                              void* d_out, int out_size, void* d_ws, size_t ws_size,
                              hipStream_t stream) {
    const float* feat = (const float*)d_in[0];
    const float* W    = (const float*)d_in[1];
    const float* bias = (const float*)d_in[2];
    float* out = (float*)d_out;
    int N = in_sizes[0] / DIMD;

    // 1) W -> frag-major fp16 in workspace (128 KB)
    w_conv_kernel<<<32, 256, 0, stream>>>(W, (f16x8*)d_ws);

    // 2) fused mask-GEMM (single fp16 pass) + per-plane peeling + output
    int grid = (int)((N + MT - 1) / MT);
    sad_mfma_kernel<<<grid, BT, 0, stream>>>(feat, bias, (const f16x8*)d_ws, out, N);
}